// Round 5
// baseline (63.509 us; speedup 1.0000x reference)
//
#include <hip/hip_runtime.h>

#define TWO_LOG2E 2.8853901817779268f   // 2*log2(e)
#define LOG2E     1.4426950408889634f

// quad_perm DPP cross-lane (stays on VALU pipe)
template<int CTRL>
__device__ __forceinline__ float dpp_qperm(float x) {
    int r = __builtin_amdgcn_update_dpp(0, __float_as_int(x), CTRL, 0xF, 0xF, true);
    return __int_as_float(r);
}

// input hs = 2*log2(e)*x; returns tanh(x) = 1 - 2/(e^{2x}+1)
__device__ __forceinline__ float tanh_pre(float hs) {
    float e = __builtin_amdgcn_exp2f(hs);
    float r = __builtin_amdgcn_rcpf(e + 1.0f);
    return fmaf(-2.0f, r, 1.0f);
}

// One thread per (edge, class); lane's class c = tid & 3.
// 2-stage software pipeline: iteration i issues idx loads for stage i+1 BEFORE
// computing stage i (hides ~900cy HBM idx latency under compute), then issues
// stage i+1 gathers AFTER compute (hides L2 gather latency under next iter).
__global__ __launch_bounds__(256, 5) void edge_mlp(
    const float* __restrict__ m,     // [N_NODES, 4, 2]
    const int*   __restrict__ eidx,  // [2, E]
    const float* __restrict__ W1,    // [4, 4, 8]
    const float* __restrict__ b1,    // [4, 8]
    const float* __restrict__ W2,    // [4, 8, 1]
    const float* __restrict__ b2,    // [4, 1]
    float*       __restrict__ out,   // [E, 4]
    const int nE)
{
    const int tid0 = blockIdx.x * blockDim.x + threadIdx.x;
    const int c = tid0 & 3;
    const int cc2 = c * 2;

    // ---- per-class weights, prescaled by 2*log2e ----
    float w1[32];                       // W1[c][i][j]*2log2e at w1[i*8+j]
    #pragma unroll
    for (int k = 0; k < 8; ++k) {
        float4 v = *(const float4*)(W1 + c*32 + 4*k);
        w1[4*k+0] = v.x * TWO_LOG2E; w1[4*k+1] = v.y * TWO_LOG2E;
        w1[4*k+2] = v.z * TWO_LOG2E; w1[4*k+3] = v.w * TWO_LOG2E;
    }
    float bb1[8];
    #pragma unroll
    for (int j = 0; j < 8; ++j) bb1[j] = b1[c*8 + j] * TWO_LOG2E;
    float w2[8];
    #pragma unroll
    for (int j = 0; j < 8; ++j) w2[j] = W2[c*8 + j] * TWO_LOG2E;
    const float b2s = b2[c] * TWO_LOG2E;

    const int* eidx1 = eidx + nE;
    const int total  = nE * 4;
    const int stride = gridDim.x * blockDim.x;   // multiple of 4 -> c constant
    constexpr int UN = 4;
    const int step = UN * stride;

    int t = tid0;
    int   row[UN], col[UN];
    float2 mc[UN], mr[UN];

    bool have = (t + (UN - 1) * stride < total);
    if (have) {
        #pragma unroll
        for (int k = 0; k < UN; ++k) {
            const int e = (t + k * stride) >> 2;
            row[k] = __builtin_nontemporal_load(eidx + e);
            col[k] = __builtin_nontemporal_load(eidx1 + e);
        }
        #pragma unroll
        for (int k = 0; k < UN; ++k) {
            mc[k] = *(const float2*)(m + (unsigned)col[k] * 8u + cc2);
            mr[k] = *(const float2*)(m + (unsigned)row[k] * 8u + cc2);
        }
    }

    while (have) {
        const int tn = t + step;
        const bool haveN = (tn + (UN - 1) * stride < total);
        int rowN[UN], colN[UN];
        if (haveN) {                       // issue next idx loads FIRST
            #pragma unroll
            for (int k = 0; k < UN; ++k) {
                const int e = (tn + k * stride) >> 2;
                rowN[k] = __builtin_nontemporal_load(eidx + e);
                colN[k] = __builtin_nontemporal_load(eidx1 + e);
            }
        }
        // ---- compute current stage (waits only on current gathers) ----
        #pragma unroll
        for (int k = 0; k < UN; ++k) {
            float o = b2s;                       // scaled domain (x 2log2e)
            #pragma unroll
            for (int j = 0; j < 8; ++j) {
                float h = bb1[j];
                h = fmaf(mc[k].x, w1[j],      h);
                h = fmaf(mc[k].y, w1[8 + j],  h);
                h = fmaf(mr[k].x, w1[16 + j], h);
                h = fmaf(mr[k].y, w1[24 + j], h);
                o = fmaf(tanh_pre(h), w2[j], o);
            }
            // eo = e^{tanh(o_true)} = 2^{log2e - 2log2e * rcp(e^{2 o_true}+1)}
            const float e2 = __builtin_amdgcn_exp2f(o);
            const float r2 = __builtin_amdgcn_rcpf(e2 + 1.0f);
            const float eo = __builtin_amdgcn_exp2f(fmaf(-TWO_LOG2E, r2, LOG2E));
            float s = eo + dpp_qperm<0xB1>(eo);      // xor 1
            s = s + dpp_qperm<0x4E>(s);              // xor 2
            __builtin_nontemporal_store(eo * __builtin_amdgcn_rcpf(s),
                                        out + (t + k * stride));
        }
        if (haveN) {                       // issue next gathers (idx arrived)
            #pragma unroll
            for (int k = 0; k < UN; ++k) {
                mc[k] = *(const float2*)(m + (unsigned)colN[k] * 8u + cc2);
                mr[k] = *(const float2*)(m + (unsigned)rowN[k] * 8u + cc2);
            }
        }
        t = tn;
        have = haveN;
    }

    // tail (empty for the bench shape: grid chosen so total == 10*UN*stride)
    for (; t < total; t += stride) {
        const int e  = t >> 2;
        const int r0 = eidx[e];
        const int c0 = eidx1[e];
        const float2 mcv = *(const float2*)(m + (unsigned)c0 * 8u + cc2);
        const float2 mrv = *(const float2*)(m + (unsigned)r0 * 8u + cc2);
        float o = b2s;
        #pragma unroll
        for (int j = 0; j < 8; ++j) {
            float h = bb1[j];
            h = fmaf(mcv.x, w1[j],      h);
            h = fmaf(mcv.y, w1[8 + j],  h);
            h = fmaf(mrv.x, w1[16 + j], h);
            h = fmaf(mrv.y, w1[24 + j], h);
            o = fmaf(tanh_pre(h), w2[j], o);
        }
        const float e2 = __builtin_amdgcn_exp2f(o);
        const float r2 = __builtin_amdgcn_rcpf(e2 + 1.0f);
        const float eo = __builtin_amdgcn_exp2f(fmaf(-TWO_LOG2E, r2, LOG2E));
        float s = eo + dpp_qperm<0xB1>(eo);
        s = s + dpp_qperm<0x4E>(s);
        out[t] = eo * __builtin_amdgcn_rcpf(s);
    }
}

extern "C" void kernel_launch(void* const* d_in, const int* in_sizes, int n_in,
                              void* d_out, int out_size, void* d_ws, size_t ws_size,
                              hipStream_t stream) {
    const float* m  = (const float*)d_in[0];
    const int* eidx = (const int*)d_in[1];
    const float* W1 = (const float*)d_in[2];
    const float* b1 = (const float*)d_in[3];
    const float* W2 = (const float*)d_in[4];
    const float* b2 = (const float*)d_in[5];
    float* out = (float*)d_out;
    const int nE = in_sizes[1] / 2;

    const int threads = 256;
    // 1250 blocks: stride=320000, total=12.8M = 10 * (4*stride) exactly ->
    // uniform 10 pipelined stages per thread, zero tail, ~5 blocks/CU.
    const int blocks  = 1250;
    hipLaunchKernelGGL(edge_mlp, dim3(blocks), dim3(threads), 0, stream,
                       m, eidx, W1, b1, W2, b2, out, nE);
}